// Round 5
// baseline (789.553 us; speedup 1.0000x reference)
//
#include <hip/hip_runtime.h>
#include <hip/hip_bf16.h>

// Problem: N=4,C=64,F=100,T=200,H=16 ; B=N*F=400, BT=80000
// Pipeline per b-chunk (NB rows): ln1 (fp32->bf16 x) -> xg GEMM (MFMA bf16,
//   bf16 out, gate-permuted, coalesced ushort4 stores) -> LSTM recurrence
//   (4 chains/wave, packed f32x2 gate math; weights kept LOOP-CARRIED via an
//   empty inline-asm identity INSIDE the loop -- r3's pre-loop pin failed:
//   VGPR_Count=44 proved the invariant weight loads were rematerialized into
//   the loop (L1-BW bound, ~1660cy/step). Loop-carried asm defs cannot be
//   remat'd, forcing all 32 f32x2 weight pairs register-resident.
//   h-broadcast via DPP row_newbcast (VALU, ~2cy); depth-4 xg prefetch) ->
//   attention (multiplicative causal mask BEFORE softmax, suffix-V trick) ->
//   combine+LN2+complex linear+LN3+PReLU+residual.
// ws: header 204800 B (bihh fp32 @0, Wih-bf16 @8192), then per chunk:
//   xr bf16 [NB][200][64], xi same, xg bf16 [24][200][NB][16][4],
//   h f32 [24][NB][200][16], att f32 [8][NB][200][16].
// Total = 204800 + NB*1,075,200.
// NOTE r4: previous submission of this exact source hit "container failed
// twice" (infra). Resubmitting unchanged to get a clean measurement of the
// loop-carried-pin theory (verification: VGPR_Count must rise to >=96).

typedef __attribute__((ext_vector_type(8))) short bf16x8;
typedef __attribute__((ext_vector_type(4))) float f32x4;
typedef __attribute__((ext_vector_type(2))) float f32x2;

static __device__ __forceinline__ float bf2f(unsigned short u) {
  return __uint_as_float(((unsigned)u) << 16);
}
static __device__ __forceinline__ unsigned short f2bfu(float x) {
  __hip_bfloat16 h = __float2bfloat16(x);
  return *(unsigned short*)&h;
}
static __device__ __forceinline__ float sigf(float x) {
  return __fdividef(1.f, 1.f + __expf(-x));
}
static __device__ __forceinline__ float tanh_(float x) {
  return 1.f - __fdividef(2.f, __expf(2.f * x) + 1.f);  // safe at +-inf
}
static __device__ __forceinline__ f32x2 hh2(float v) {
  f32x2 r; r.x = v; r.y = v; return r;
}

// Broadcast lane (row-base + I) of h to all 16 lanes of its row.
// ROW_NEWBCAST:I = dpp_ctrl 0x150+I (CDNA2+/gfx950). Bit-exact equal to
// __shfl(h, (lane&48)+I, 64) since chains occupy aligned 16-lane rows.
template <int CTRL>
static __device__ __forceinline__ float dpp_bcast(float x) {
  int xi = __float_as_int(x);
  int r = __builtin_amdgcn_update_dpp(xi, xi, CTRL, 0xF, 0xF, false);
  return __int_as_float(r);
}

// ---------------- kernel A: LN1 over C -> xr/xi bf16 [bl][t][c]
__global__ __launch_bounds__(256) void k_ln1(const float* __restrict__ in,
    const float* __restrict__ w, const float* __restrict__ bsh,
    unsigned short* __restrict__ xr, unsigned short* __restrict__ xi, int b0) {
  __shared__ float is[64][101];   // [c][(tloc,ri)]
  __shared__ float os[100][65];   // [(tloc,ri)][c]
  int bid = blockIdx.x;
  int nfl = bid >> 2, tile = bid & 3;         // NB nf-local x 4 tiles of 50 t
  int nf = b0 + nfl;
  int t0 = tile * 50;
  int n = nf / 100, f = nf - n * 100;
  int tid = threadIdx.x;
  for (int i = 0; i < 7; ++i) {               // 64 rows x 25 float4
    int idx = tid + i * 256;
    if (idx < 1600) {
      int c = idx / 25, q = idx - c * 25;
      float4 v = *(const float4*)(in + (size_t)((n * 64 + c) * 100 + f) * 400
                                  + t0 * 2 + q * 4);
      is[c][q*4+0] = v.x; is[c][q*4+1] = v.y; is[c][q*4+2] = v.z; is[c][q*4+3] = v.w;
    }
  }
  __syncthreads();
  if (tid < 100) {
    float s = 0.f, ss = 0.f;
    #pragma unroll
    for (int c = 0; c < 64; ++c) { float v = is[c][tid]; s += v; ss += v * v; }
    float mean = s * 0.015625f;
    float var  = ss * 0.015625f - mean * mean;
    float rstd = rsqrtf(var + 1e-5f);
    #pragma unroll
    for (int c = 0; c < 64; ++c)
      os[tid][c] = (is[c][tid] - mean) * rstd * w[c] + bsh[c];
  }
  __syncthreads();
  for (int ri = 0; ri < 2; ++ri) {
    unsigned short* dst = ri ? xi : xr;
    for (int i = 0; i < 4; ++i) {             // 50 rows x 16 ushort4 per ri
      int idx = tid + i * 256;
      if (idx < 800) {
        int t = idx >> 4, q = idx & 15;
        ushort4 v;
        v.x = f2bfu(os[t*2+ri][q*4+0]); v.y = f2bfu(os[t*2+ri][q*4+1]);
        v.z = f2bfu(os[t*2+ri][q*4+2]); v.w = f2bfu(os[t*2+ri][q*4+3]);
        *(ushort4*)(dst + ((size_t)nfl * 200 + t0 + t) * 64 + q * 4) = v;
      }
    }
  }
}

// ---------------- prep: bihh = bih + bhh ; wbf = bf16(Wih)
__global__ void k_prep(const float* __restrict__ bih, const float* __restrict__ bhh,
                       const float* __restrict__ Wih, float* __restrict__ bihh,
                       unsigned short* __restrict__ wbf) {
  int i = blockIdx.x * 256 + threadIdx.x;
  if (i < 1536) bihh[i] = bih[i] + bhh[i];
  if (i < 98304) wbf[i] = f2bfu(Wih[i]);
}

// ---------------- kernel B: xg = x_sel @ Wih[l]^T + bihh[l] via MFMA bf16.
// One wave = 16-row m-strip x all 64 j. A-frag: m=lane&15, k=quad*8+e.
// B-frag: n=lane&15, k=quad*8+e. D: col=lane&15, row=quad*4+r. Lane holds
// col n=k for every jt -> accumulate 4 gate results, one ushort4 store/row.
__global__ __launch_bounds__(256) void k_xg(const unsigned short* __restrict__ xr,
    const unsigned short* __restrict__ xi, const unsigned short* __restrict__ wbf,
    const float* __restrict__ bihh, unsigned short* __restrict__ xg,
    int M, int NB, int nsb) {
  int tid = threadIdx.x;
  int wave = tid >> 6, lane = tid & 63;
  int bid = blockIdx.x;
  int l = bid / nsb, sb = bid - l * nsb;
  int sub = sb * 4 + wave;
  int m0 = sub * 16;
  if (m0 >= M) return;
  int sel = (0xE54770 >> l) & 1;                 // per-lstm real/imag selection
  const unsigned short* xs = sel ? xi : xr;
  int n = lane & 15, q = lane >> 4;
  int mr = m0 + n; if (mr >= M) mr = M - 1;      // clamp A rows (stores guarded)
  const unsigned short* xrow = xs + (size_t)mr * 64;
  bf16x8 a0 = *(const bf16x8*)(xrow + q * 8);        // c = q*8+e
  bf16x8 a1 = *(const bf16x8*)(xrow + 32 + q * 8);   // c = 32+q*8+e
  int mq = m0 + q * 4;
  int bl = mq / 200, tt = mq - bl * 200;
  size_t ob[4]; bool okm[4];
  #pragma unroll
  for (int r = 0; r < 4; ++r) {
    okm[r] = (mq + r) < M;
    ob[r] = ((size_t)(l * 200 + tt) * NB + bl) * 64;
    ++tt; if (tt == 200) { tt = 0; ++bl; }
  }
  const unsigned short* wbase = wbf + l * 4096;
  f32x4 acc[4];
  float bi[4];
  #pragma unroll
  for (int jt = 0; jt < 4; ++jt) {               // j = jt*16 + n ; k=n, g=jt
    const unsigned short* wrow = wbase + (jt * 16 + n) * 64;
    bf16x8 b0 = *(const bf16x8*)(wrow + q * 8);
    bf16x8 b1 = *(const bf16x8*)(wrow + 32 + q * 8);
    f32x4 a = {0.f, 0.f, 0.f, 0.f};
    a = __builtin_amdgcn_mfma_f32_16x16x32_bf16(a0, b0, a, 0, 0, 0);
    acc[jt] = __builtin_amdgcn_mfma_f32_16x16x32_bf16(a1, b1, a, 0, 0, 0);
    bi[jt] = bihh[l * 64 + jt * 16 + n];
  }
  #pragma unroll
  for (int r = 0; r < 4; ++r) {
    if (!okm[r]) continue;
    ushort4 o;
    o.x = f2bfu(acc[0][r] + bi[0]);
    o.y = f2bfu(acc[1][r] + bi[1]);
    o.z = f2bfu(acc[2][r] + bi[2]);
    o.w = f2bfu(acc[3][r] + bi[3]);
    *(ushort4*)(xg + ob[r] + n * 4) = o;         // coalesced 8B store
  }
}

// ---------------- kernel R: LSTM recurrence. 1 wave per block = 4 chains.
// lane=(bl=lane>>4 chain, k=lane&15). Lane computes all 4 gate pre-acts as
// two f32x2 (packed-fma-friendly). Weights in 32 NAMED f32x2 regs, made
// LOOP-CARRIED via an empty asm identity at the top of each outer iteration:
// iteration i's weight values are defined by iteration i-1's asm output, so
// the allocator can neither rematerialize the invariant loads (r2/r3 failure
// mode, VGPR_Count 56/44) nor cheaply spill. h-broadcast via DPP
// row_newbcast (VALU) - no DS pipe. 4 accumulator chains halve FMA depth.
// Depth-4 xg prefetch.
__global__ __launch_bounds__(64, 2) void k_lstm(const unsigned short* __restrict__ xg,
    const float* __restrict__ Whh, float* __restrict__ hbuf, int NB) {
  int lane = threadIdx.x;
  int bl = lane >> 4, k = lane & 15;
  int chain = blockIdx.x * 4 + bl;        // 24*NB chains, 6*NB blocks
  int l = chain / NB, b = chain - l * NB;
  const float* W = Whh + (size_t)l * 1024;
  const float* wi = W + k * 16;           // gate i row
  const float* wf = W + (16 + k) * 16;    // gate f row
  const float* wg = W + (32 + k) * 16;    // gate g row
  const float* wo = W + (48 + k) * 16;    // gate o row
#define DECLW(i) f32x2 wa##i = {wi[i], wf[i]}; f32x2 wb##i = {wg[i], wo[i]};
  DECLW(0) DECLW(1) DECLW(2) DECLW(3) DECLW(4) DECLW(5) DECLW(6) DECLW(7)
  DECLW(8) DECLW(9) DECLW(10) DECLW(11) DECLW(12) DECLW(13) DECLW(14) DECLW(15)
#undef DECLW
  const unsigned short* xgp = xg + ((size_t)l * 200 * NB + b) * 64 + k * 4;
  size_t tstride = (size_t)NB * 64;       // ushorts per t step
  float* hp = hbuf + ((size_t)l * NB + b) * 3200 + k;
  float h = 0.f, c = 0.f;
  ushort4 b0 = *(const ushort4*)(xgp);
  ushort4 b1 = *(const ushort4*)(xgp + tstride);
  ushort4 b2 = *(const ushort4*)(xgp + 2 * tstride);
  ushort4 b3 = *(const ushort4*)(xgp + 3 * tstride);
  int tcur = 0;
#define HV(i) dpp_bcast<0x150 + i>(h)
#define LSTEP(BUF, TN) { \
  float hv0  = HV(0),  hv1  = HV(1),  hv2  = HV(2),  hv3  = HV(3);  \
  float hv4  = HV(4),  hv5  = HV(5),  hv6  = HV(6),  hv7  = HV(7);  \
  float hv8  = HV(8),  hv9  = HV(9),  hv10 = HV(10), hv11 = HV(11); \
  float hv12 = HV(12), hv13 = HV(13), hv14 = HV(14), hv15 = HV(15); \
  f32x2 pA = {bf2f(BUF.x), bf2f(BUF.y)}; \
  f32x2 qA = {bf2f(BUF.z), bf2f(BUF.w)}; \
  f32x2 pB = {0.f, 0.f}, qB = {0.f, 0.f}; \
  pA += wa0  * hh2(hv0);  pB += wa1  * hh2(hv1);  \
  qA += wb0  * hh2(hv0);  qB += wb1  * hh2(hv1);  \
  pA += wa2  * hh2(hv2);  pB += wa3  * hh2(hv3);  \
  qA += wb2  * hh2(hv2);  qB += wb3  * hh2(hv3);  \
  pA += wa4  * hh2(hv4);  pB += wa5  * hh2(hv5);  \
  qA += wb4  * hh2(hv4);  qB += wb5  * hh2(hv5);  \
  pA += wa6  * hh2(hv6);  pB += wa7  * hh2(hv7);  \
  qA += wb6  * hh2(hv6);  qB += wb7  * hh2(hv7);  \
  pA += wa8  * hh2(hv8);  pB += wa9  * hh2(hv9);  \
  qA += wb8  * hh2(hv8);  qB += wb9  * hh2(hv9);  \
  pA += wa10 * hh2(hv10); pB += wa11 * hh2(hv11); \
  qA += wb10 * hh2(hv10); qB += wb11 * hh2(hv11); \
  pA += wa12 * hh2(hv12); pB += wa13 * hh2(hv13); \
  qA += wb12 * hh2(hv12); qB += wb13 * hh2(hv13); \
  pA += wa14 * hh2(hv14); pB += wa15 * hh2(hv15); \
  qA += wb14 * hh2(hv14); qB += wb15 * hh2(hv15); \
  f32x2 p01 = pA + pB, p23 = qA + qB; \
  float ig_ = sigf(p01.x), fg_ = sigf(p01.y); \
  float gg_ = tanh_(p23.x), og_ = sigf(p23.y); \
  c = fg_ * c + ig_ * gg_; \
  h = og_ * tanh_(c); \
  hp[tcur * 16] = h; ++tcur; \
  BUF = *(const ushort4*)(xgp + (size_t)(TN) * tstride); }
  for (int it = 0; it < 50; ++it) {
    // Loop-carried identity: forces all 32 weight pairs to stay in VGPRs
    // (asm defs can't be rematerialized; spilling would cost per-iteration).
    asm volatile("" : "+v"(wa0), "+v"(wa1), "+v"(wa2), "+v"(wa3),
                      "+v"(wa4), "+v"(wa5), "+v"(wa6), "+v"(wa7),
                      "+v"(wa8), "+v"(wa9), "+v"(wa10), "+v"(wa11),
                      "+v"(wa12), "+v"(wa13), "+v"(wa14), "+v"(wa15));
    asm volatile("" : "+v"(wb0), "+v"(wb1), "+v"(wb2), "+v"(wb3),
                      "+v"(wb4), "+v"(wb5), "+v"(wb6), "+v"(wb7),
                      "+v"(wb8), "+v"(wb9), "+v"(wb10), "+v"(wb11),
                      "+v"(wb12), "+v"(wb13), "+v"(wb14), "+v"(wb15));
    int t4 = it * 4;
    int n0 = t4 + 4; if (n0 > 199) n0 = 199;
    int n1 = t4 + 5; if (n1 > 199) n1 = 199;
    int n2 = t4 + 6; if (n2 > 199) n2 = 199;
    int n3 = t4 + 7; if (n3 > 199) n3 = 199;
    LSTEP(b0, n0)
    LSTEP(b1, n1)
    LSTEP(b2, n2)
    LSTEP(b3, n3)
  }
#undef LSTEP
#undef HV
}

// ---------------- kernel C: attention per (branch, bl). Multiplicative causal
// mask before softmax: masked s get weight exp(0); handled via suffix-V init.
__global__ __launch_bounds__(256) void k_attn(const float* __restrict__ hbuf,
                                              float* __restrict__ att, int NB) {
  __shared__ float Q[200][17];
  __shared__ float K[200][16];
  __shared__ float V[200][16];
  __shared__ float Vs[200][17];
  int bid = blockIdx.x;                 // 8 br x NB
  int br = bid / NB, b = bid - br * NB;
  int tid = threadIdx.x;
  const float* qg = hbuf + ((size_t)(br * 3 + 0) * NB + b) * 3200;
  const float* kg = hbuf + ((size_t)(br * 3 + 1) * NB + b) * 3200;
  const float* vg = hbuf + ((size_t)(br * 3 + 2) * NB + b) * 3200;
  for (int i = 0; i < 4; ++i) {         // 200 rows x 4 f4 each of Q,K,V
    int idx = tid + i * 256;
    if (idx < 800) {
      int t = idx >> 2, q = idx & 3;
      float4 a = *(const float4*)(qg + t * 16 + q * 4);
      Q[t][q*4+0] = a.x; Q[t][q*4+1] = a.y; Q[t][q*4+2] = a.z; Q[t][q*4+3] = a.w;
      *(float4*)&K[t][q * 4] = *(const float4*)(kg + t * 16 + q * 4);
      *(float4*)&V[t][q * 4] = *(const float4*)(vg + t * 16 + q * 4);
    }
  }
  __syncthreads();
  if (tid < 16) {                       // suffix sums of V
    float acc = 0.f;
    Vs[199][tid] = 0.f;
    for (int t = 198; t >= 0; --t) { acc += V[t + 1][tid]; Vs[t][tid] = acc; }
  }
  __syncthreads();
  if (tid < 200) {
    int t = tid;
    float q0[16], va[16];
    #pragma unroll
    for (int k = 0; k < 16; ++k) q0[k] = Q[t][k] * 0.25f;   // fold /sqrt(16)
    #pragma unroll
    for (int k = 0; k < 16; ++k) va[k] = Vs[t][k];          // masked: weight exp(0)=1
    float S = (float)(199 - t);
    for (int s = 0; s <= t; ++s) {
      float e = 0.f;
      #pragma unroll
      for (int k = 0; k < 16; ++k) e += q0[k] * K[s][k];
      float wgt = __expf(e);
      S += wgt;
      #pragma unroll
      for (int k = 0; k < 16; ++k) va[k] += wgt * V[s][k];
    }
    float inv = __fdividef(1.f, S);
    float* dst = att + (((size_t)br * NB + b) * 200 + t) * 16;
    #pragma unroll
    for (int q = 0; q < 4; ++q) {
      float4 v; v.x = va[q*4+0]*inv; v.y = va[q*4+1]*inv;
      v.z = va[q*4+2]*inv; v.w = va[q*4+3]*inv;
      *(float4*)(dst + q * 4) = v;
    }
  }
}

// ---------------- kernel D: combine branches + LN2 + complex linear + LN3 +
// PReLU + residual, with LDS transpose for coalesced [N,C,F,T,2] IO.
__global__ __launch_bounds__(256) void k_out(const float* __restrict__ att,
    const float* __restrict__ in,
    const float* __restrict__ ln2w, const float* __restrict__ ln2b,
    const float* __restrict__ lrw, const float* __restrict__ lrb,
    const float* __restrict__ liw, const float* __restrict__ lib,
    const float* __restrict__ ln3w, const float* __restrict__ ln3b,
    const float* __restrict__ pa, float* __restrict__ out, int b0, int NB) {
  __shared__ float as_[8][40][17];
  __shared__ float ys[40][2][17];
  __shared__ float zs[64][81];
  int bid = blockIdx.x;                 // NB nf-local x 5 tiles of 40 t
  int nfl = bid / 5, tile = bid - nfl * 5;
  int nf = b0 + nfl;
  int t0 = tile * 40;
  int n = nf / 100, f = nf - n * 100;
  int tid = threadIdx.x;
  for (int i = 0; i < 5; ++i) {         // att: 8 br x 40 t x 4 f4
    int idx = tid + i * 256;
    int br = idx / 160, r = idx - br * 160;
    int t = r >> 2, q = r & 3;
    float4 v = *(const float4*)(att + (((size_t)br * NB + nfl) * 200 + t0 + t) * 16 + q * 4);
    as_[br][t][q*4+0] = v.x; as_[br][t][q*4+1] = v.y;
    as_[br][t][q*4+2] = v.z; as_[br][t][q*4+3] = v.w;
  }
  __syncthreads();
  if (tid < 80) {                       // combine + LN2 per (t,ri)
    int t = tid >> 1, ri = tid & 1;
    float vv[16]; float s = 0.f, ss = 0.f;
    #pragma unroll
    for (int k = 0; k < 16; ++k) {
      float v;
      if (ri == 0) v = as_[0][t][k] - as_[1][t][k] - as_[2][t][k] - as_[3][t][k];
      else         v = as_[4][t][k] + as_[5][t][k] + as_[6][t][k] - as_[7][t][k];
      vv[k] = v; s += v; ss += v * v;
    }
    float mean = s * 0.0625f;
    float var  = ss * 0.0625f - mean * mean;
    float rstd = rsqrtf(var + 1e-5f);
    #pragma unroll
    for (int k = 0; k < 16; ++k)
      ys[t][ri][k] = (vv[k] - mean) * rstd * ln2w[k] + ln2b[k];
  }
  __syncthreads();
  // complex linear 16->64 + LN3 over c (wave = 64 lanes = c) + PReLU
  int wv = tid >> 6, cc = tid & 63;
  float lr[16], li[16];
  #pragma unroll
  for (int q = 0; q < 4; ++q) {
    float4 v = *(const float4*)(lrw + cc * 16 + q * 4);
    lr[q*4+0] = v.x; lr[q*4+1] = v.y; lr[q*4+2] = v.z; lr[q*4+3] = v.w;
    float4 u = *(const float4*)(liw + cc * 16 + q * 4);
    li[q*4+0] = u.x; li[q*4+1] = u.y; li[q*4+2] = u.z; li[q*4+3] = u.w;
  }
  float brc = lrb[cc], bic = lib[cc];
  float w3 = ln3w[cc], b3 = ln3b[cc];
  float aP = pa[0];
  for (int tt = wv; tt < 40; tt += 4) {
    float zr = brc - bic, zi = brc + bic;
    #pragma unroll
    for (int k = 0; k < 16; ++k) {
      float yr = ys[tt][0][k], yi = ys[tt][1][k];
      zr += yr * lr[k] - yi * li[k];
      zi += yi * lr[k] + yr * li[k];
    }
    float s1 = zr, s2 = zr * zr, s3 = zi, s4 = zi * zi;
    #pragma unroll
    for (int m = 1; m < 64; m <<= 1) {
      s1 += __shfl_xor(s1, m, 64);
      s2 += __shfl_xor(s2, m, 64);
      s3 += __shfl_xor(s3, m, 64);
      s4 += __shfl_xor(s4, m, 64);
    }
    float mr = s1 * 0.015625f, vr = s2 * 0.015625f - mr * mr;
    float mi = s3 * 0.015625f, vi = s4 * 0.015625f - mi * mi;
    float r1 = (zr - mr) * rsqrtf(vr + 1e-5f) * w3 + b3;
    float r2 = (zi - mi) * rsqrtf(vi + 1e-5f) * w3 + b3;
    r1 = r1 >= 0.f ? r1 : aP * r1;
    r2 = r2 >= 0.f ? r2 : aP * r2;
    zs[cc][tt * 2 + 0] = r1;
    zs[cc][tt * 2 + 1] = r2;
  }
  __syncthreads();
  for (int i = 0; i < 5; ++i) {         // residual + coalesced write
    int idx = tid + i * 256;            // 64 c x 20 f4
    int c = idx / 20, q = idx - c * 20;
    size_t gaddr = (size_t)((n * 64 + c) * 100 + f) * 400 + t0 * 2 + q * 4;
    float4 v = *(const float4*)(in + gaddr);
    float4 z;
    z.x = zs[c][q*4+0] + v.x; z.y = zs[c][q*4+1] + v.y;
    z.z = zs[c][q*4+2] + v.z; z.w = zs[c][q*4+3] + v.w;
    *(float4*)(out + gaddr) = z;
  }
}

extern "C" void kernel_launch(void* const* d_in, const int* in_sizes, int n_in,
                              void* d_out, int out_size, void* d_ws, size_t ws_size,
                              hipStream_t stream) {
  (void)in_sizes; (void)n_in; (void)out_size;
  const float* inputs = (const float*)d_in[0];
  const float* Wih  = (const float*)d_in[1];
  const float* Whh  = (const float*)d_in[2];
  const float* bih  = (const float*)d_in[3];
  const float* bhh  = (const float*)d_in[4];
  const float* ln1w = (const float*)d_in[5];
  const float* ln1b = (const float*)d_in[6];
  const float* ln2w = (const float*)d_in[7];
  const float* ln2b = (const float*)d_in[8];
  const float* lrw  = (const float*)d_in[9];
  const float* lrb  = (const float*)d_in[10];
  const float* liw  = (const float*)d_in[11];
  const float* lib  = (const float*)d_in[12];
  const float* ln3w = (const float*)d_in[13];
  const float* ln3b = (const float*)d_in[14];
  const float* pa   = (const float*)d_in[15];
  float* out = (float*)d_out;
  char* ws = (char*)d_ws;

  // pick largest chunk NB (400,200,100,50,25) whose buffers fit ws_size
  int NB = 400;
  while (NB > 25 && 204800ull + (size_t)NB * 1075200ull > ws_size) NB /= 2;
  int nch = 400 / NB;

  float* bihh = (float*)(ws + 0);                        // 6 KB
  unsigned short* wbf = (unsigned short*)(ws + 8192);    // 192 KB bf16 Wih
  size_t o_xr = 204800;
  size_t o_xi = o_xr + (size_t)NB * 25600;
  size_t o_xg = o_xi + (size_t)NB * 25600;
  size_t o_h  = o_xg + (size_t)NB * 614400;
  size_t o_at = o_h  + (size_t)NB * 307200;
  unsigned short* xr = (unsigned short*)(ws + o_xr);
  unsigned short* xi = (unsigned short*)(ws + o_xi);
  unsigned short* xg = (unsigned short*)(ws + o_xg);
  float* hbuf = (float*)(ws + o_h);
  float* att  = (float*)(ws + o_at);

  k_prep<<<384, 256, 0, stream>>>(bih, bhh, Wih, bihh, wbf);
  int M = NB * 200;
  int nsb = (M + 63) >> 6;              // 64 m-rows per block (4 waves x 16)
  for (int ch = 0; ch < nch; ++ch) {
    int b0 = ch * NB;
    k_ln1 <<<NB * 4,   256, 0, stream>>>(inputs, ln1w, ln1b, xr, xi, b0);
    k_xg  <<<24 * nsb, 256, 0, stream>>>(xr, xi, wbf, bihh, xg, M, NB, nsb);
    k_lstm<<<NB * 6,    64, 0, stream>>>(xg, Whh, hbuf, NB);   // 1 wave = 4 chains
    k_attn<<<8 * NB,   256, 0, stream>>>(hbuf, att, NB);
    k_out <<<NB * 5,   256, 0, stream>>>(att, inputs, ln2w, ln2b, lrw, lrb,
                                         liw, lib, ln3w, ln3b, pa, out, b0, NB);
  }
}

// Round 6
// 769.729 us; speedup vs baseline: 1.0258x; 1.0258x over previous
//
#include <hip/hip_runtime.h>
#include <hip/hip_bf16.h>

// Problem: N=4,C=64,F=100,T=200,H=16 ; B=N*F=400, BT=80000
// Pipeline per b-chunk (NB rows): ln1 (fp32->bf16 x) -> xg GEMM (MFMA bf16,
//   bf16 out, gate-permuted, coalesced ushort4 stores) -> LSTM recurrence
//   (4 chains/wave; Whh staged in LDS, padded conflict-free: r2-r5 proved the
//   register allocator ALWAYS demotes the 64-VGPR weight set and re-loads it
//   every step (VGPR_Count 44-56 across 3 pinning attempts, ~1650cy/step
//   L1-reload-bound). LDS makes each reload a broadcast ds_read_b64 on
//   distinct banks instead of an L1 global load. h-broadcast via DPP
//   row_newbcast; depth-4 xg prefetch) -> attention (multiplicative causal
//   mask BEFORE softmax, suffix-V trick) -> combine+LN2+complex linear+LN3+
//   PReLU+residual.
// ws: header 204800 B (bihh fp32 @0, Wih-bf16 @8192), then per chunk:
//   xr bf16 [NB][200][64], xi same, xg bf16 [24][200][NB][16][4],
//   h f32 [24][NB][200][16], att f32 [8][NB][200][16].
// Total = 204800 + NB*1,075,200.

typedef __attribute__((ext_vector_type(8))) short bf16x8;
typedef __attribute__((ext_vector_type(4))) float f32x4;
typedef __attribute__((ext_vector_type(2))) float f32x2;

static __device__ __forceinline__ float bf2f(unsigned short u) {
  return __uint_as_float(((unsigned)u) << 16);
}
static __device__ __forceinline__ unsigned short f2bfu(float x) {
  __hip_bfloat16 h = __float2bfloat16(x);
  return *(unsigned short*)&h;
}
static __device__ __forceinline__ float sigf(float x) {
  return __fdividef(1.f, 1.f + __expf(-x));
}
static __device__ __forceinline__ float tanh_(float x) {
  return 1.f - __fdividef(2.f, __expf(2.f * x) + 1.f);  // safe at +-inf
}
static __device__ __forceinline__ f32x2 hh2(float v) {
  f32x2 r; r.x = v; r.y = v; return r;
}

// Broadcast lane (row-base + I) of h to all 16 lanes of its row.
// ROW_NEWBCAST:I = dpp_ctrl 0x150+I (CDNA2+/gfx950). Bit-exact equal to
// __shfl(h, (lane&48)+I, 64) since chains occupy aligned 16-lane rows.
template <int CTRL>
static __device__ __forceinline__ float dpp_bcast(float x) {
  int xi = __float_as_int(x);
  int r = __builtin_amdgcn_update_dpp(xi, xi, CTRL, 0xF, 0xF, false);
  return __int_as_float(r);
}

// ---------------- kernel A: LN1 over C -> xr/xi bf16 [bl][t][c]
__global__ __launch_bounds__(256) void k_ln1(const float* __restrict__ in,
    const float* __restrict__ w, const float* __restrict__ bsh,
    unsigned short* __restrict__ xr, unsigned short* __restrict__ xi, int b0) {
  __shared__ float is[64][101];   // [c][(tloc,ri)]
  __shared__ float os[100][65];   // [(tloc,ri)][c]
  int bid = blockIdx.x;
  int nfl = bid >> 2, tile = bid & 3;         // NB nf-local x 4 tiles of 50 t
  int nf = b0 + nfl;
  int t0 = tile * 50;
  int n = nf / 100, f = nf - n * 100;
  int tid = threadIdx.x;
  for (int i = 0; i < 7; ++i) {               // 64 rows x 25 float4
    int idx = tid + i * 256;
    if (idx < 1600) {
      int c = idx / 25, q = idx - c * 25;
      float4 v = *(const float4*)(in + (size_t)((n * 64 + c) * 100 + f) * 400
                                  + t0 * 2 + q * 4);
      is[c][q*4+0] = v.x; is[c][q*4+1] = v.y; is[c][q*4+2] = v.z; is[c][q*4+3] = v.w;
    }
  }
  __syncthreads();
  if (tid < 100) {
    float s = 0.f, ss = 0.f;
    #pragma unroll
    for (int c = 0; c < 64; ++c) { float v = is[c][tid]; s += v; ss += v * v; }
    float mean = s * 0.015625f;
    float var  = ss * 0.015625f - mean * mean;
    float rstd = rsqrtf(var + 1e-5f);
    #pragma unroll
    for (int c = 0; c < 64; ++c)
      os[tid][c] = (is[c][tid] - mean) * rstd * w[c] + bsh[c];
  }
  __syncthreads();
  for (int ri = 0; ri < 2; ++ri) {
    unsigned short* dst = ri ? xi : xr;
    for (int i = 0; i < 4; ++i) {             // 50 rows x 16 ushort4 per ri
      int idx = tid + i * 256;
      if (idx < 800) {
        int t = idx >> 4, q = idx & 15;
        ushort4 v;
        v.x = f2bfu(os[t*2+ri][q*4+0]); v.y = f2bfu(os[t*2+ri][q*4+1]);
        v.z = f2bfu(os[t*2+ri][q*4+2]); v.w = f2bfu(os[t*2+ri][q*4+3]);
        *(ushort4*)(dst + ((size_t)nfl * 200 + t0 + t) * 64 + q * 4) = v;
      }
    }
  }
}

// ---------------- prep: bihh = bih + bhh ; wbf = bf16(Wih)
__global__ void k_prep(const float* __restrict__ bih, const float* __restrict__ bhh,
                       const float* __restrict__ Wih, float* __restrict__ bihh,
                       unsigned short* __restrict__ wbf) {
  int i = blockIdx.x * 256 + threadIdx.x;
  if (i < 1536) bihh[i] = bih[i] + bhh[i];
  if (i < 98304) wbf[i] = f2bfu(Wih[i]);
}

// ---------------- kernel B: xg = x_sel @ Wih[l]^T + bihh[l] via MFMA bf16.
// One wave = 16-row m-strip x all 64 j. A-frag: m=lane&15, k=quad*8+e.
// B-frag: n=lane&15, k=quad*8+e. D: col=lane&15, row=quad*4+r. Lane holds
// col n=k for every jt -> accumulate 4 gate results, one ushort4 store/row.
__global__ __launch_bounds__(256) void k_xg(const unsigned short* __restrict__ xr,
    const unsigned short* __restrict__ xi, const unsigned short* __restrict__ wbf,
    const float* __restrict__ bihh, unsigned short* __restrict__ xg,
    int M, int NB, int nsb) {
  int tid = threadIdx.x;
  int wave = tid >> 6, lane = tid & 63;
  int bid = blockIdx.x;
  int l = bid / nsb, sb = bid - l * nsb;
  int sub = sb * 4 + wave;
  int m0 = sub * 16;
  if (m0 >= M) return;
  int sel = (0xE54770 >> l) & 1;                 // per-lstm real/imag selection
  const unsigned short* xs = sel ? xi : xr;
  int n = lane & 15, q = lane >> 4;
  int mr = m0 + n; if (mr >= M) mr = M - 1;      // clamp A rows (stores guarded)
  const unsigned short* xrow = xs + (size_t)mr * 64;
  bf16x8 a0 = *(const bf16x8*)(xrow + q * 8);        // c = q*8+e
  bf16x8 a1 = *(const bf16x8*)(xrow + 32 + q * 8);   // c = 32+q*8+e
  int mq = m0 + q * 4;
  int bl = mq / 200, tt = mq - bl * 200;
  size_t ob[4]; bool okm[4];
  #pragma unroll
  for (int r = 0; r < 4; ++r) {
    okm[r] = (mq + r) < M;
    ob[r] = ((size_t)(l * 200 + tt) * NB + bl) * 64;
    ++tt; if (tt == 200) { tt = 0; ++bl; }
  }
  const unsigned short* wbase = wbf + l * 4096;
  f32x4 acc[4];
  float bi[4];
  #pragma unroll
  for (int jt = 0; jt < 4; ++jt) {               // j = jt*16 + n ; k=n, g=jt
    const unsigned short* wrow = wbase + (jt * 16 + n) * 64;
    bf16x8 b0 = *(const bf16x8*)(wrow + q * 8);
    bf16x8 b1 = *(const bf16x8*)(wrow + 32 + q * 8);
    f32x4 a = {0.f, 0.f, 0.f, 0.f};
    a = __builtin_amdgcn_mfma_f32_16x16x32_bf16(a0, b0, a, 0, 0, 0);
    acc[jt] = __builtin_amdgcn_mfma_f32_16x16x32_bf16(a1, b1, a, 0, 0, 0);
    bi[jt] = bihh[l * 64 + jt * 16 + n];
  }
  #pragma unroll
  for (int r = 0; r < 4; ++r) {
    if (!okm[r]) continue;
    ushort4 o;
    o.x = f2bfu(acc[0][r] + bi[0]);
    o.y = f2bfu(acc[1][r] + bi[1]);
    o.z = f2bfu(acc[2][r] + bi[2]);
    o.w = f2bfu(acc[3][r] + bi[3]);
    *(ushort4*)(xg + ob[r] + n * 4) = o;         // coalesced 8B store
  }
}

// ---------------- kernel R: LSTM recurrence. 1 wave per block = 4 chains of
// the SAME l (grid = 24 x ceil(NB/4); duplicate chains clamp to b=NB-1 and
// write identical data). lane=(bl=lane>>4 chain, k=lane&15).
// Whh[l] staged once in LDS as f32x2 wl[2][16][17]:
//   wl[0][k][i] = {W[k][i], W[16+k][i]}   (gates i,f)
//   wl[1][k][i] = {W[32+k][i], W[48+k][i]} (gates g,o)
// Row stride 17*8=136B -> lane k hits banks {2k,2k+1}: 16 k-values cover all
// 32 banks; the 4 chain-groups read identical addresses (broadcast). The
// allocator's reload-preference (r2-r5: VGPR 44-56, refuses to keep 64 weight
// VGPRs) now costs a conflict-free ds_read_b64 instead of an L1 global load.
// h-broadcast via DPP row_newbcast. 4 accumulator chains. Depth-4 xg prefetch.
__global__ __launch_bounds__(64) void k_lstm(const unsigned short* __restrict__ xg,
    const float* __restrict__ Whh, float* __restrict__ hbuf, int NB, int nbq) {
  __shared__ f32x2 wl[2][16][17];
  int lane = threadIdx.x;
  int bl = lane >> 4, k = lane & 15;
  int lq = blockIdx.x / nbq, q4 = blockIdx.x - lq * nbq;
  int b = q4 * 4 + bl; if (b >= NB) b = NB - 1;  // dup chains: identical writes
  int l = lq;
  const float* Wg = Whh + (size_t)l * 1024;
  for (int idx = lane; idx < 1024; idx += 64) {  // coalesced one-time fill
    int row = idx >> 4, col = idx & 15;
    int gate = row >> 4, kk = row & 15;
    ((float*)&wl[gate >> 1][kk][col])[gate & 1] = Wg[idx];
  }
  __syncthreads();
  const f32x2* wla = wl[0][k];
  const f32x2* wlb = wl[1][k];
  const unsigned short* xgp = xg + ((size_t)l * 200 * NB + b) * 64 + k * 4;
  size_t tstride = (size_t)NB * 64;       // ushorts per t step
  float* hp = hbuf + ((size_t)l * NB + b) * 3200 + k;
  float h = 0.f, c = 0.f;
  ushort4 b0 = *(const ushort4*)(xgp);
  ushort4 b1 = *(const ushort4*)(xgp + tstride);
  ushort4 b2 = *(const ushort4*)(xgp + 2 * tstride);
  ushort4 b3 = *(const ushort4*)(xgp + 3 * tstride);
  int tcur = 0;
#define HV(i) dpp_bcast<0x150 + i>(h)
#define LSTEP(BUF, TN) { \
  float hv0  = HV(0),  hv1  = HV(1),  hv2  = HV(2),  hv3  = HV(3);  \
  float hv4  = HV(4),  hv5  = HV(5),  hv6  = HV(6),  hv7  = HV(7);  \
  float hv8  = HV(8),  hv9  = HV(9),  hv10 = HV(10), hv11 = HV(11); \
  float hv12 = HV(12), hv13 = HV(13), hv14 = HV(14), hv15 = HV(15); \
  f32x2 pA = {bf2f(BUF.x), bf2f(BUF.y)}; \
  f32x2 qA = {bf2f(BUF.z), bf2f(BUF.w)}; \
  f32x2 pB = {0.f, 0.f}, qB = {0.f, 0.f}; \
  pA += wla[0]  * hh2(hv0);  pB += wla[1]  * hh2(hv1);  \
  qA += wlb[0]  * hh2(hv0);  qB += wlb[1]  * hh2(hv1);  \
  pA += wla[2]  * hh2(hv2);  pB += wla[3]  * hh2(hv3);  \
  qA += wlb[2]  * hh2(hv2);  qB += wlb[3]  * hh2(hv3);  \
  pA += wla[4]  * hh2(hv4);  pB += wla[5]  * hh2(hv5);  \
  qA += wlb[4]  * hh2(hv4);  qB += wlb[5]  * hh2(hv5);  \
  pA += wla[6]  * hh2(hv6);  pB += wla[7]  * hh2(hv7);  \
  qA += wlb[6]  * hh2(hv6);  qB += wlb[7]  * hh2(hv7);  \
  pA += wla[8]  * hh2(hv8);  pB += wla[9]  * hh2(hv9);  \
  qA += wlb[8]  * hh2(hv8);  qB += wlb[9]  * hh2(hv9);  \
  pA += wla[10] * hh2(hv10); pB += wla[11] * hh2(hv11); \
  qA += wlb[10] * hh2(hv10); qB += wlb[11] * hh2(hv11); \
  pA += wla[12] * hh2(hv12); pB += wla[13] * hh2(hv13); \
  qA += wlb[12] * hh2(hv12); qB += wlb[13] * hh2(hv13); \
  pA += wla[14] * hh2(hv14); pB += wla[15] * hh2(hv15); \
  qA += wlb[14] * hh2(hv14); qB += wlb[15] * hh2(hv15); \
  f32x2 p01 = pA + pB, p23 = qA + qB; \
  float ig_ = sigf(p01.x), fg_ = sigf(p01.y); \
  float gg_ = tanh_(p23.x), og_ = sigf(p23.y); \
  c = fg_ * c + ig_ * gg_; \
  h = og_ * tanh_(c); \
  hp[tcur * 16] = h; ++tcur; \
  BUF = *(const ushort4*)(xgp + (size_t)(TN) * tstride); }
  for (int it = 0; it < 50; ++it) {
    int t4 = it * 4;
    int n0 = t4 + 4; if (n0 > 199) n0 = 199;
    int n1 = t4 + 5; if (n1 > 199) n1 = 199;
    int n2 = t4 + 6; if (n2 > 199) n2 = 199;
    int n3 = t4 + 7; if (n3 > 199) n3 = 199;
    LSTEP(b0, n0)
    LSTEP(b1, n1)
    LSTEP(b2, n2)
    LSTEP(b3, n3)
  }
#undef LSTEP
#undef HV
}

// ---------------- kernel C: attention per (branch, bl). Multiplicative causal
// mask before softmax: masked s get weight exp(0); handled via suffix-V init.
__global__ __launch_bounds__(256) void k_attn(const float* __restrict__ hbuf,
                                              float* __restrict__ att, int NB) {
  __shared__ float Q[200][17];
  __shared__ float K[200][16];
  __shared__ float V[200][16];
  __shared__ float Vs[200][17];
  int bid = blockIdx.x;                 // 8 br x NB
  int br = bid / NB, b = bid - br * NB;
  int tid = threadIdx.x;
  const float* qg = hbuf + ((size_t)(br * 3 + 0) * NB + b) * 3200;
  const float* kg = hbuf + ((size_t)(br * 3 + 1) * NB + b) * 3200;
  const float* vg = hbuf + ((size_t)(br * 3 + 2) * NB + b) * 3200;
  for (int i = 0; i < 4; ++i) {         // 200 rows x 4 f4 each of Q,K,V
    int idx = tid + i * 256;
    if (idx < 800) {
      int t = idx >> 2, q = idx & 3;
      float4 a = *(const float4*)(qg + t * 16 + q * 4);
      Q[t][q*4+0] = a.x; Q[t][q*4+1] = a.y; Q[t][q*4+2] = a.z; Q[t][q*4+3] = a.w;
      *(float4*)&K[t][q * 4] = *(const float4*)(kg + t * 16 + q * 4);
      *(float4*)&V[t][q * 4] = *(const float4*)(vg + t * 16 + q * 4);
    }
  }
  __syncthreads();
  if (tid < 16) {                       // suffix sums of V
    float acc = 0.f;
    Vs[199][tid] = 0.f;
    for (int t = 198; t >= 0; --t) { acc += V[t + 1][tid]; Vs[t][tid] = acc; }
  }
  __syncthreads();
  if (tid < 200) {
    int t = tid;
    float q0[16], va[16];
    #pragma unroll
    for (int k = 0; k < 16; ++k) q0[k] = Q[t][k] * 0.25f;   // fold /sqrt(16)
    #pragma unroll
    for (int k = 0; k < 16; ++k) va[k] = Vs[t][k];          // masked: weight exp(0)=1
    float S = (float)(199 - t);
    for (int s = 0; s <= t; ++s) {
      float e = 0.f;
      #pragma unroll
      for (int k = 0; k < 16; ++k) e += q0[k] * K[s][k];
      float wgt = __expf(e);
      S += wgt;
      #pragma unroll
      for (int k = 0; k < 16; ++k) va[k] += wgt * V[s][k];
    }
    float inv = __fdividef(1.f, S);
    float* dst = att + (((size_t)br * NB + b) * 200 + t) * 16;
    #pragma unroll
    for (int q = 0; q < 4; ++q) {
      float4 v; v.x = va[q*4+0]*inv; v.y = va[q*4+1]*inv;
      v.z = va[q*4+2]*inv; v.w = va[q*4+3]*inv;
      *(float4*)(dst + q * 4) = v;
    }
  }
}

// ---------------- kernel D: combine branches + LN2 + complex linear + LN3 +
// PReLU + residual, with LDS transpose for coalesced [N,C,F,T,2] IO.
__global__ __launch_bounds__(256) void k_out(const float* __restrict__ att,
    const float* __restrict__ in,
    const float* __restrict__ ln2w, const float* __restrict__ ln2b,
    const float* __restrict__ lrw, const float* __restrict__ lrb,
    const float* __restrict__ liw, const float* __restrict__ lib,
    const float* __restrict__ ln3w, const float* __restrict__ ln3b,
    const float* __restrict__ pa, float* __restrict__ out, int b0, int NB) {
  __shared__ float as_[8][40][17];
  __shared__ float ys[40][2][17];
  __shared__ float zs[64][81];
  int bid = blockIdx.x;                 // NB nf-local x 5 tiles of 40 t
  int nfl = bid / 5, tile = bid - nfl * 5;
  int nf = b0 + nfl;
  int t0 = tile * 40;
  int n = nf / 100, f = nf - n * 100;
  int tid = threadIdx.x;
  for (int i = 0; i < 5; ++i) {         // att: 8 br x 40 t x 4 f4
    int idx = tid + i * 256;
    int br = idx / 160, r = idx - br * 160;
    int t = r >> 2, q = r & 3;
    float4 v = *(const float4*)(att + (((size_t)br * NB + nfl) * 200 + t0 + t) * 16 + q * 4);
    as_[br][t][q*4+0] = v.x; as_[br][t][q*4+1] = v.y;
    as_[br][t][q*4+2] = v.z; as_[br][t][q*4+3] = v.w;
  }
  __syncthreads();
  if (tid < 80) {                       // combine + LN2 per (t,ri)
    int t = tid >> 1, ri = tid & 1;
    float vv[16]; float s = 0.f, ss = 0.f;
    #pragma unroll
    for (int k = 0; k < 16; ++k) {
      float v;
      if (ri == 0) v = as_[0][t][k] - as_[1][t][k] - as_[2][t][k] - as_[3][t][k];
      else         v = as_[4][t][k] + as_[5][t][k] + as_[6][t][k] - as_[7][t][k];
      vv[k] = v; s += v; ss += v * v;
    }
    float mean = s * 0.0625f;
    float var  = ss * 0.0625f - mean * mean;
    float rstd = rsqrtf(var + 1e-5f);
    #pragma unroll
    for (int k = 0; k < 16; ++k)
      ys[t][ri][k] = (vv[k] - mean) * rstd * ln2w[k] + ln2b[k];
  }
  __syncthreads();
  // complex linear 16->64 + LN3 over c (wave = 64 lanes = c) + PReLU
  int wv = tid >> 6, cc = tid & 63;
  float lr[16], li[16];
  #pragma unroll
  for (int q = 0; q < 4; ++q) {
    float4 v = *(const float4*)(lrw + cc * 16 + q * 4);
    lr[q*4+0] = v.x; lr[q*4+1] = v.y; lr[q*4+2] = v.z; lr[q*4+3] = v.w;
    float4 u = *(const float4*)(liw + cc * 16 + q * 4);
    li[q*4+0] = u.x; li[q*4+1] = u.y; li[q*4+2] = u.z; li[q*4+3] = u.w;
  }
  float brc = lrb[cc], bic = lib[cc];
  float w3 = ln3w[cc], b3 = ln3b[cc];
  float aP = pa[0];
  for (int tt = wv; tt < 40; tt += 4) {
    float zr = brc - bic, zi = brc + bic;
    #pragma unroll
    for (int k = 0; k < 16; ++k) {
      float yr = ys[tt][0][k], yi = ys[tt][1][k];
      zr += yr * lr[k] - yi * li[k];
      zi += yi * lr[k] + yr * li[k];
    }
    float s1 = zr, s2 = zr * zr, s3 = zi, s4 = zi * zi;
    #pragma unroll
    for (int m = 1; m < 64; m <<= 1) {
      s1 += __shfl_xor(s1, m, 64);
      s2 += __shfl_xor(s2, m, 64);
      s3 += __shfl_xor(s3, m, 64);
      s4 += __shfl_xor(s4, m, 64);
    }
    float mr = s1 * 0.015625f, vr = s2 * 0.015625f - mr * mr;
    float mi = s3 * 0.015625f, vi = s4 * 0.015625f - mi * mi;
    float r1 = (zr - mr) * rsqrtf(vr + 1e-5f) * w3 + b3;
    float r2 = (zi - mi) * rsqrtf(vi + 1e-5f) * w3 + b3;
    r1 = r1 >= 0.f ? r1 : aP * r1;
    r2 = r2 >= 0.f ? r2 : aP * r2;
    zs[cc][tt * 2 + 0] = r1;
    zs[cc][tt * 2 + 1] = r2;
  }
  __syncthreads();
  for (int i = 0; i < 5; ++i) {         // residual + coalesced write
    int idx = tid + i * 256;            // 64 c x 20 f4
    int c = idx / 20, q = idx - c * 20;
    size_t gaddr = (size_t)((n * 64 + c) * 100 + f) * 400 + t0 * 2 + q * 4;
    float4 v = *(const float4*)(in + gaddr);
    float4 z;
    z.x = zs[c][q*4+0] + v.x; z.y = zs[c][q*4+1] + v.y;
    z.z = zs[c][q*4+2] + v.z; z.w = zs[c][q*4+3] + v.w;
    *(float4*)(out + gaddr) = z;
  }
}

extern "C" void kernel_launch(void* const* d_in, const int* in_sizes, int n_in,
                              void* d_out, int out_size, void* d_ws, size_t ws_size,
                              hipStream_t stream) {
  (void)in_sizes; (void)n_in; (void)out_size;
  const float* inputs = (const float*)d_in[0];
  const float* Wih  = (const float*)d_in[1];
  const float* Whh  = (const float*)d_in[2];
  const float* bih  = (const float*)d_in[3];
  const float* bhh  = (const float*)d_in[4];
  const float* ln1w = (const float*)d_in[5];
  const float* ln1b = (const float*)d_in[6];
  const float* ln2w = (const float*)d_in[7];
  const float* ln2b = (const float*)d_in[8];
  const float* lrw  = (const float*)d_in[9];
  const float* lrb  = (const float*)d_in[10];
  const float* liw  = (const float*)d_in[11];
  const float* lib  = (const float*)d_in[12];
  const float* ln3w = (const float*)d_in[13];
  const float* ln3b = (const float*)d_in[14];
  const float* pa   = (const float*)d_in[15];
  float* out = (float*)d_out;
  char* ws = (char*)d_ws;

  // pick largest chunk NB (400,200,100,50,25) whose buffers fit ws_size
  int NB = 400;
  while (NB > 25 && 204800ull + (size_t)NB * 1075200ull > ws_size) NB /= 2;
  int nch = 400 / NB;

  float* bihh = (float*)(ws + 0);                        // 6 KB
  unsigned short* wbf = (unsigned short*)(ws + 8192);    // 192 KB bf16 Wih
  size_t o_xr = 204800;
  size_t o_xi = o_xr + (size_t)NB * 25600;
  size_t o_xg = o_xi + (size_t)NB * 25600;
  size_t o_h  = o_xg + (size_t)NB * 614400;
  size_t o_at = o_h  + (size_t)NB * 307200;
  unsigned short* xr = (unsigned short*)(ws + o_xr);
  unsigned short* xi = (unsigned short*)(ws + o_xi);
  unsigned short* xg = (unsigned short*)(ws + o_xg);
  float* hbuf = (float*)(ws + o_h);
  float* att  = (float*)(ws + o_at);

  k_prep<<<384, 256, 0, stream>>>(bih, bhh, Wih, bihh, wbf);
  int M = NB * 200;
  int nsb = (M + 63) >> 6;              // 64 m-rows per block (4 waves x 16)
  int nbq = (NB + 3) >> 2;              // 4-chain groups per l
  for (int ch = 0; ch < nch; ++ch) {
    int b0 = ch * NB;
    k_ln1 <<<NB * 4,   256, 0, stream>>>(inputs, ln1w, ln1b, xr, xi, b0);
    k_xg  <<<24 * nsb, 256, 0, stream>>>(xr, xi, wbf, bihh, xg, M, NB, nsb);
    k_lstm<<<24 * nbq,  64, 0, stream>>>(xg, Whh, hbuf, NB, nbq);  // LDS weights
    k_attn<<<8 * NB,   256, 0, stream>>>(hbuf, att, NB);
    k_out <<<NB * 5,   256, 0, stream>>>(att, inputs, ln2w, ln2b, lrw, lrb,
                                         liw, lib, ln3w, ln3b, pa, out, b0, NB);
  }
}

// Round 7
// 507.776 us; speedup vs baseline: 1.5549x; 1.5159x over previous
//
#include <hip/hip_runtime.h>
#include <hip/hip_bf16.h>

// Problem: N=4,C=64,F=100,T=200,H=16 ; B=N*F=400, BT=80000
// r7 restructure: the xg intermediate (614KB/b) is GONE. r2-r6 proved k_lstm
// is latency-bound at 0.6 waves/SIMD (Occupancy 9%, VALUBusy 47%, per-step
// ~1600cy invariant under DS<->DPP and L1<->LDS weight swaps); the xg buffer
// forced NB=100 -> 4 serialized chunk launches of only 600 waves each.
// Now k_lstm fuses the input GEMM: per 4 steps, 8 MFMAs (A-rows = 4 b x 4 dt
// of LN1'd x, B = Wih bf16, bias in C-operand) produce the pre-acts for
// chain q, unit c, step dt=r exactly in lane (q,c) -- the k_xg-proven D
// mapping (col=lane&15, row=quad*4+r). Software-pipelined one group ahead.
// Pre-acts are now fp32 (more accurate than old bf16 xg). Per-b ws drops to
// 460800B -> NB=400/200 -> one or two k_lstm launches with 2400 waves
// (2.3/SIMD) instead of 4x600.
// Pipeline per chunk: ln1 (fp32->bf16 xr/xi) -> k_lstm (fused GEMM+recurrence;
//   Whh staged in LDS conflict-free, h-broadcast via DPP row_newbcast) ->
//   attention (mult. causal mask BEFORE softmax, suffix-V) -> combine+LN2+
//   complex linear+LN3+PReLU+residual.
// ws: header 204800 B (bihh fp32 @0, Wih-bf16 @8192), then per chunk:
//   xr bf16 [NB][200][64], xi same, h f32 [24][NB][200][16],
//   att f32 [8][NB][200][16].  Total = 204800 + NB*460800.

typedef __attribute__((ext_vector_type(8))) short bf16x8;
typedef __attribute__((ext_vector_type(4))) float f32x4;
typedef __attribute__((ext_vector_type(2))) float f32x2;

static __device__ __forceinline__ float bf2f(unsigned short u) {
  return __uint_as_float(((unsigned)u) << 16);
}
static __device__ __forceinline__ unsigned short f2bfu(float x) {
  __hip_bfloat16 h = __float2bfloat16(x);
  return *(unsigned short*)&h;
}
static __device__ __forceinline__ float sigf(float x) {
  return __fdividef(1.f, 1.f + __expf(-x));
}
static __device__ __forceinline__ float tanh_(float x) {
  return 1.f - __fdividef(2.f, __expf(2.f * x) + 1.f);  // safe at +-inf
}
static __device__ __forceinline__ f32x2 hh2(float v) {
  f32x2 r; r.x = v; r.y = v; return r;
}

// Broadcast lane (row-base + I) of h to all 16 lanes of its row.
// ROW_NEWBCAST:I = dpp_ctrl 0x150+I (CDNA2+/gfx950). Bit-exact equal to
// __shfl(h, (lane&48)+I, 64) since chains occupy aligned 16-lane rows.
template <int CTRL>
static __device__ __forceinline__ float dpp_bcast(float x) {
  int xi = __float_as_int(x);
  int r = __builtin_amdgcn_update_dpp(xi, xi, CTRL, 0xF, 0xF, false);
  return __int_as_float(r);
}

// ---------------- kernel A: LN1 over C -> xr/xi bf16 [bl][t][c]
__global__ __launch_bounds__(256) void k_ln1(const float* __restrict__ in,
    const float* __restrict__ w, const float* __restrict__ bsh,
    unsigned short* __restrict__ xr, unsigned short* __restrict__ xi, int b0) {
  __shared__ float is[64][101];   // [c][(tloc,ri)]
  __shared__ float os[100][65];   // [(tloc,ri)][c]
  int bid = blockIdx.x;
  int nfl = bid >> 2, tile = bid & 3;         // NB nf-local x 4 tiles of 50 t
  int nf = b0 + nfl;
  int t0 = tile * 50;
  int n = nf / 100, f = nf - n * 100;
  int tid = threadIdx.x;
  for (int i = 0; i < 7; ++i) {               // 64 rows x 25 float4
    int idx = tid + i * 256;
    if (idx < 1600) {
      int c = idx / 25, q = idx - c * 25;
      float4 v = *(const float4*)(in + (size_t)((n * 64 + c) * 100 + f) * 400
                                  + t0 * 2 + q * 4);
      is[c][q*4+0] = v.x; is[c][q*4+1] = v.y; is[c][q*4+2] = v.z; is[c][q*4+3] = v.w;
    }
  }
  __syncthreads();
  if (tid < 100) {
    float s = 0.f, ss = 0.f;
    #pragma unroll
    for (int c = 0; c < 64; ++c) { float v = is[c][tid]; s += v; ss += v * v; }
    float mean = s * 0.015625f;
    float var  = ss * 0.015625f - mean * mean;
    float rstd = rsqrtf(var + 1e-5f);
    #pragma unroll
    for (int c = 0; c < 64; ++c)
      os[tid][c] = (is[c][tid] - mean) * rstd * w[c] + bsh[c];
  }
  __syncthreads();
  for (int ri = 0; ri < 2; ++ri) {
    unsigned short* dst = ri ? xi : xr;
    for (int i = 0; i < 4; ++i) {             // 50 rows x 16 ushort4 per ri
      int idx = tid + i * 256;
      if (idx < 800) {
        int t = idx >> 4, q = idx & 15;
        ushort4 v;
        v.x = f2bfu(os[t*2+ri][q*4+0]); v.y = f2bfu(os[t*2+ri][q*4+1]);
        v.z = f2bfu(os[t*2+ri][q*4+2]); v.w = f2bfu(os[t*2+ri][q*4+3]);
        *(ushort4*)(dst + ((size_t)nfl * 200 + t0 + t) * 64 + q * 4) = v;
      }
    }
  }
}

// ---------------- prep: bihh = bih + bhh ; wbf = bf16(Wih)
__global__ void k_prep(const float* __restrict__ bih, const float* __restrict__ bhh,
                       const float* __restrict__ Wih, float* __restrict__ bihh,
                       unsigned short* __restrict__ wbf) {
  int i = blockIdx.x * 256 + threadIdx.x;
  if (i < 1536) bihh[i] = bih[i] + bhh[i];
  if (i < 98304) wbf[i] = f2bfu(Wih[i]);
}

// ---------------- kernel R: fused input-GEMM + LSTM recurrence.
// 1 wave = 4 chains of the SAME l (grid 24 x ceil(NB/4); dup chains clamp to
// b=NB-1, identical writes). lane = (q=lane>>4 chain, c=lane&15 unit).
// Every 4 steps, MGROUP computes pre-acts via 8 MFMAs:
//   A rows m = b_local*4+dt of x_sel (bf16), B = Wih[l] rows jt*16+c,
//   C = bias splat. D mapping (col=lane&15=unit c, row=q*4+r -> chain q,
//   dt=r) lands each value in its consumer lane. One group pipelined ahead;
//   A-loads for group g+2 issued at group g.
// Whh[l] staged in LDS f32x2 wl[2][16][17] (conflict-free broadcast, r6).
// h-broadcast via DPP row_newbcast.
__global__ __launch_bounds__(64) void k_lstm(const unsigned short* __restrict__ xr,
    const unsigned short* __restrict__ xi, const unsigned short* __restrict__ wbf,
    const float* __restrict__ bihh, const float* __restrict__ Whh,
    float* __restrict__ hbuf, int NB, int nbq) {
  __shared__ f32x2 wl[2][16][17];
  int lane = threadIdx.x;
  int q = lane >> 4, c = lane & 15;       // chain-in-block, unit
  int lq = blockIdx.x / nbq, q4 = blockIdx.x - lq * nbq;
  int l = lq;
  int b = q4 * 4 + q; if (b >= NB) b = NB - 1;   // dup chains: identical writes
  const float* Wg = Whh + (size_t)l * 1024;
  for (int idx = lane; idx < 1024; idx += 64) {  // coalesced one-time fill
    int row = idx >> 4, col = idx & 15;
    int gate = row >> 4, kk = row & 15;
    ((float*)&wl[gate >> 1][kk][col])[gate & 1] = Wg[idx];
  }
  __syncthreads();
  const f32x2* wla = wl[0][c];
  const f32x2* wlb = wl[1][c];
  int sel = (0xE54770 >> l) & 1;                 // per-lstm real/imag selection
  const unsigned short* xs = sel ? xi : xr;
  // A-frag source: lane (q,c) holds x row m = c -> b_local=c>>2, dt=c&3.
  int ba = q4 * 4 + (c >> 2); if (ba >= NB) ba = NB - 1;
  const unsigned short* ap2 = xs + ((size_t)ba * 200 + (c & 3)) * 64 + q * 8;
  // B-frag source: Wih row jt*16 + c, channels q*8+e (jt stride 1024 ushorts)
  const unsigned short* wrow = wbf + l * 4096 + c * 64 + q * 8;
  // bias splats (C-operand of first MFMA of each gate)
  float bv0 = bihh[l * 64 + c], bv1 = bihh[l * 64 + 16 + c];
  float bv2 = bihh[l * 64 + 32 + c], bv3 = bihh[l * 64 + 48 + c];
  f32x4 zb0 = {bv0, bv0, bv0, bv0}, zb1 = {bv1, bv1, bv1, bv1};
  f32x4 zb2 = {bv2, bv2, bv2, bv2}, zb3 = {bv3, bv3, bv3, bv3};
  float* hp = hbuf + ((size_t)l * NB + b) * 3200 + c;
  float h = 0.f, cs = 0.f;
  int tcur = 0;
#define MG1(DST, OFS, ZB, A0v, A1v) { \
  bf16x8 w0_ = *(const bf16x8*)(wrow + OFS); \
  bf16x8 w1_ = *(const bf16x8*)(wrow + OFS + 32); \
  f32x4 t_ = __builtin_amdgcn_mfma_f32_16x16x32_bf16(A0v, w0_, ZB, 0, 0, 0); \
  DST = __builtin_amdgcn_mfma_f32_16x16x32_bf16(A1v, w1_, t_, 0, 0, 0); }
#define MGROUP(D0, D1, D2, D3, A0v, A1v) \
  MG1(D0, 0, zb0, A0v, A1v) MG1(D1, 1024, zb1, A0v, A1v) \
  MG1(D2, 2048, zb2, A0v, A1v) MG1(D3, 3072, zb3, A0v, A1v)
#define HV(i) dpp_bcast<0x150 + i>(h)
#define LSTEP2(AC0, AC1, AC2, AC3, FLD) { \
  float hv0  = HV(0),  hv1  = HV(1),  hv2  = HV(2),  hv3  = HV(3);  \
  float hv4  = HV(4),  hv5  = HV(5),  hv6  = HV(6),  hv7  = HV(7);  \
  float hv8  = HV(8),  hv9  = HV(9),  hv10 = HV(10), hv11 = HV(11); \
  float hv12 = HV(12), hv13 = HV(13), hv14 = HV(14), hv15 = HV(15); \
  f32x2 pA = {AC0.FLD, AC1.FLD}; \
  f32x2 qA = {AC2.FLD, AC3.FLD}; \
  f32x2 pB = {0.f, 0.f}, qB = {0.f, 0.f}; \
  pA += wla[0]  * hh2(hv0);  pB += wla[1]  * hh2(hv1);  \
  qA += wlb[0]  * hh2(hv0);  qB += wlb[1]  * hh2(hv1);  \
  pA += wla[2]  * hh2(hv2);  pB += wla[3]  * hh2(hv3);  \
  qA += wlb[2]  * hh2(hv2);  qB += wlb[3]  * hh2(hv3);  \
  pA += wla[4]  * hh2(hv4);  pB += wla[5]  * hh2(hv5);  \
  qA += wlb[4]  * hh2(hv4);  qB += wlb[5]  * hh2(hv5);  \
  pA += wla[6]  * hh2(hv6);  pB += wla[7]  * hh2(hv7);  \
  qA += wlb[6]  * hh2(hv6);  qB += wlb[7]  * hh2(hv7);  \
  pA += wla[8]  * hh2(hv8);  pB += wla[9]  * hh2(hv9);  \
  qA += wlb[8]  * hh2(hv8);  qB += wlb[9]  * hh2(hv9);  \
  pA += wla[10] * hh2(hv10); pB += wla[11] * hh2(hv11); \
  qA += wlb[10] * hh2(hv10); qB += wlb[11] * hh2(hv11); \
  pA += wla[12] * hh2(hv12); pB += wla[13] * hh2(hv13); \
  qA += wlb[12] * hh2(hv12); qB += wlb[13] * hh2(hv13); \
  pA += wla[14] * hh2(hv14); pB += wla[15] * hh2(hv15); \
  qA += wlb[14] * hh2(hv14); qB += wlb[15] * hh2(hv15); \
  f32x2 p01 = pA + pB, p23 = qA + qB; \
  float ig_ = sigf(p01.x), fg_ = sigf(p01.y); \
  float gg_ = tanh_(p23.x), og_ = sigf(p23.y); \
  cs = fg_ * cs + ig_ * gg_; \
  h = og_ * tanh_(cs); \
  hp[tcur * 16] = h; ++tcur; }
  // prologue: group 0 pre-acts; prefetch A of group 1
  bf16x8 a0 = *(const bf16x8*)(ap2), a1 = *(const bf16x8*)(ap2 + 32);
  f32x4 c0, c1, c2, c3, n0, n1, n2, n3;
  MGROUP(c0, c1, c2, c3, a0, a1);
  ap2 += 256;
  a0 = *(const bf16x8*)(ap2); a1 = *(const bf16x8*)(ap2 + 32);
  for (int g = 0; g < 50; ++g) {
    LSTEP2(c0, c1, c2, c3, x)
    LSTEP2(c0, c1, c2, c3, y)
    MGROUP(n0, n1, n2, n3, a0, a1);      // pre-acts for group g+1
    if (g < 48) ap2 += 256;              // A of group g+2 (clamped at end)
    a0 = *(const bf16x8*)(ap2); a1 = *(const bf16x8*)(ap2 + 32);
    LSTEP2(c0, c1, c2, c3, z)
    LSTEP2(c0, c1, c2, c3, w)
    c0 = n0; c1 = n1; c2 = n2; c3 = n3;
  }
#undef LSTEP2
#undef HV
#undef MGROUP
#undef MG1
}

// ---------------- kernel C: attention per (branch, bl). Multiplicative causal
// mask before softmax: masked s get weight exp(0); handled via suffix-V init.
__global__ __launch_bounds__(256) void k_attn(const float* __restrict__ hbuf,
                                              float* __restrict__ att, int NB) {
  __shared__ float Q[200][17];
  __shared__ float K[200][16];
  __shared__ float V[200][16];
  __shared__ float Vs[200][17];
  int bid = blockIdx.x;                 // 8 br x NB
  int br = bid / NB, b = bid - br * NB;
  int tid = threadIdx.x;
  const float* qg = hbuf + ((size_t)(br * 3 + 0) * NB + b) * 3200;
  const float* kg = hbuf + ((size_t)(br * 3 + 1) * NB + b) * 3200;
  const float* vg = hbuf + ((size_t)(br * 3 + 2) * NB + b) * 3200;
  for (int i = 0; i < 4; ++i) {         // 200 rows x 4 f4 each of Q,K,V
    int idx = tid + i * 256;
    if (idx < 800) {
      int t = idx >> 2, q = idx & 3;
      float4 a = *(const float4*)(qg + t * 16 + q * 4);
      Q[t][q*4+0] = a.x; Q[t][q*4+1] = a.y; Q[t][q*4+2] = a.z; Q[t][q*4+3] = a.w;
      *(float4*)&K[t][q * 4] = *(const float4*)(kg + t * 16 + q * 4);
      *(float4*)&V[t][q * 4] = *(const float4*)(vg + t * 16 + q * 4);
    }
  }
  __syncthreads();
  if (tid < 16) {                       // suffix sums of V
    float acc = 0.f;
    Vs[199][tid] = 0.f;
    for (int t = 198; t >= 0; --t) { acc += V[t + 1][tid]; Vs[t][tid] = acc; }
  }
  __syncthreads();
  if (tid < 200) {
    int t = tid;
    float q0[16], va[16];
    #pragma unroll
    for (int k = 0; k < 16; ++k) q0[k] = Q[t][k] * 0.25f;   // fold /sqrt(16)
    #pragma unroll
    for (int k = 0; k < 16; ++k) va[k] = Vs[t][k];          // masked: weight exp(0)=1
    float S = (float)(199 - t);
    for (int s = 0; s <= t; ++s) {
      float e = 0.f;
      #pragma unroll
      for (int k = 0; k < 16; ++k) e += q0[k] * K[s][k];
      float wgt = __expf(e);
      S += wgt;
      #pragma unroll
      for (int k = 0; k < 16; ++k) va[k] += wgt * V[s][k];
    }
    float inv = __fdividef(1.f, S);
    float* dst = att + (((size_t)br * NB + b) * 200 + t) * 16;
    #pragma unroll
    for (int q = 0; q < 4; ++q) {
      float4 v; v.x = va[q*4+0]*inv; v.y = va[q*4+1]*inv;
      v.z = va[q*4+2]*inv; v.w = va[q*4+3]*inv;
      *(float4*)(dst + q * 4) = v;
    }
  }
}

// ---------------- kernel D: combine branches + LN2 + complex linear + LN3 +
// PReLU + residual, with LDS transpose for coalesced [N,C,F,T,2] IO.
__global__ __launch_bounds__(256) void k_out(const float* __restrict__ att,
    const float* __restrict__ in,
    const float* __restrict__ ln2w, const float* __restrict__ ln2b,
    const float* __restrict__ lrw, const float* __restrict__ lrb,
    const float* __restrict__ liw, const float* __restrict__ lib,
    const float* __restrict__ ln3w, const float* __restrict__ ln3b,
    const float* __restrict__ pa, float* __restrict__ out, int b0, int NB) {
  __shared__ float as_[8][40][17];
  __shared__ float ys[40][2][17];
  __shared__ float zs[64][81];
  int bid = blockIdx.x;                 // NB nf-local x 5 tiles of 40 t
  int nfl = bid / 5, tile = bid - nfl * 5;
  int nf = b0 + nfl;
  int t0 = tile * 40;
  int n = nf / 100, f = nf - n * 100;
  int tid = threadIdx.x;
  for (int i = 0; i < 5; ++i) {         // att: 8 br x 40 t x 4 f4
    int idx = tid + i * 256;
    int br = idx / 160, r = idx - br * 160;
    int t = r >> 2, q = r & 3;
    float4 v = *(const float4*)(att + (((size_t)br * NB + nfl) * 200 + t0 + t) * 16 + q * 4);
    as_[br][t][q*4+0] = v.x; as_[br][t][q*4+1] = v.y;
    as_[br][t][q*4+2] = v.z; as_[br][t][q*4+3] = v.w;
  }
  __syncthreads();
  if (tid < 80) {                       // combine + LN2 per (t,ri)
    int t = tid >> 1, ri = tid & 1;
    float vv[16]; float s = 0.f, ss = 0.f;
    #pragma unroll
    for (int k = 0; k < 16; ++k) {
      float v;
      if (ri == 0) v = as_[0][t][k] - as_[1][t][k] - as_[2][t][k] - as_[3][t][k];
      else         v = as_[4][t][k] + as_[5][t][k] + as_[6][t][k] - as_[7][t][k];
      vv[k] = v; s += v; ss += v * v;
    }
    float mean = s * 0.0625f;
    float var  = ss * 0.0625f - mean * mean;
    float rstd = rsqrtf(var + 1e-5f);
    #pragma unroll
    for (int k = 0; k < 16; ++k)
      ys[t][ri][k] = (vv[k] - mean) * rstd * ln2w[k] + ln2b[k];
  }
  __syncthreads();
  // complex linear 16->64 + LN3 over c (wave = 64 lanes = c) + PReLU
  int wv = tid >> 6, cc = tid & 63;
  float lr[16], li[16];
  #pragma unroll
  for (int q = 0; q < 4; ++q) {
    float4 v = *(const float4*)(lrw + cc * 16 + q * 4);
    lr[q*4+0] = v.x; lr[q*4+1] = v.y; lr[q*4+2] = v.z; lr[q*4+3] = v.w;
    float4 u = *(const float4*)(liw + cc * 16 + q * 4);
    li[q*4+0] = u.x; li[q*4+1] = u.y; li[q*4+2] = u.z; li[q*4+3] = u.w;
  }
  float brc = lrb[cc], bic = lib[cc];
  float w3 = ln3w[cc], b3 = ln3b[cc];
  float aP = pa[0];
  for (int tt = wv; tt < 40; tt += 4) {
    float zr = brc - bic, zi = brc + bic;
    #pragma unroll
    for (int k = 0; k < 16; ++k) {
      float yr = ys[tt][0][k], yi = ys[tt][1][k];
      zr += yr * lr[k] - yi * li[k];
      zi += yi * lr[k] + yr * li[k];
    }
    float s1 = zr, s2 = zr * zr, s3 = zi, s4 = zi * zi;
    #pragma unroll
    for (int m = 1; m < 64; m <<= 1) {
      s1 += __shfl_xor(s1, m, 64);
      s2 += __shfl_xor(s2, m, 64);
      s3 += __shfl_xor(s3, m, 64);
      s4 += __shfl_xor(s4, m, 64);
    }
    float mr = s1 * 0.015625f, vr = s2 * 0.015625f - mr * mr;
    float mi = s3 * 0.015625f, vi = s4 * 0.015625f - mi * mi;
    float r1 = (zr - mr) * rsqrtf(vr + 1e-5f) * w3 + b3;
    float r2 = (zi - mi) * rsqrtf(vi + 1e-5f) * w3 + b3;
    r1 = r1 >= 0.f ? r1 : aP * r1;
    r2 = r2 >= 0.f ? r2 : aP * r2;
    zs[cc][tt * 2 + 0] = r1;
    zs[cc][tt * 2 + 1] = r2;
  }
  __syncthreads();
  for (int i = 0; i < 5; ++i) {         // residual + coalesced write
    int idx = tid + i * 256;            // 64 c x 20 f4
    int c = idx / 20, q = idx - c * 20;
    size_t gaddr = (size_t)((n * 64 + c) * 100 + f) * 400 + t0 * 2 + q * 4;
    float4 v = *(const float4*)(in + gaddr);
    float4 z;
    z.x = zs[c][q*4+0] + v.x; z.y = zs[c][q*4+1] + v.y;
    z.z = zs[c][q*4+2] + v.z; z.w = zs[c][q*4+3] + v.w;
    *(float4*)(out + gaddr) = z;
  }
}

extern "C" void kernel_launch(void* const* d_in, const int* in_sizes, int n_in,
                              void* d_out, int out_size, void* d_ws, size_t ws_size,
                              hipStream_t stream) {
  (void)in_sizes; (void)n_in; (void)out_size;
  const float* inputs = (const float*)d_in[0];
  const float* Wih  = (const float*)d_in[1];
  const float* Whh  = (const float*)d_in[2];
  const float* bih  = (const float*)d_in[3];
  const float* bhh  = (const float*)d_in[4];
  const float* ln1w = (const float*)d_in[5];
  const float* ln1b = (const float*)d_in[6];
  const float* ln2w = (const float*)d_in[7];
  const float* ln2b = (const float*)d_in[8];
  const float* lrw  = (const float*)d_in[9];
  const float* lrb  = (const float*)d_in[10];
  const float* liw  = (const float*)d_in[11];
  const float* lib  = (const float*)d_in[12];
  const float* ln3w = (const float*)d_in[13];
  const float* ln3b = (const float*)d_in[14];
  const float* pa   = (const float*)d_in[15];
  float* out = (float*)d_out;
  char* ws = (char*)d_ws;

  // pick largest chunk NB (400,200,100,50,25) whose buffers fit ws_size
  // per-b: xr+xi 51200 + h 307200 + att 102400 = 460800 B (xg is gone)
  int NB = 400;
  while (NB > 25 && 204800ull + (size_t)NB * 460800ull > ws_size) NB /= 2;
  int nch = 400 / NB;

  float* bihh = (float*)(ws + 0);                        // 6 KB
  unsigned short* wbf = (unsigned short*)(ws + 8192);    // 192 KB bf16 Wih
  size_t o_xr = 204800;
  size_t o_xi = o_xr + (size_t)NB * 25600;
  size_t o_h  = o_xi + (size_t)NB * 25600;
  size_t o_at = o_h  + (size_t)NB * 307200;
  unsigned short* xr = (unsigned short*)(ws + o_xr);
  unsigned short* xi = (unsigned short*)(ws + o_xi);
  float* hbuf = (float*)(ws + o_h);
  float* att  = (float*)(ws + o_at);

  k_prep<<<384, 256, 0, stream>>>(bih, bhh, Wih, bihh, wbf);
  int nbq = (NB + 3) >> 2;              // 4-chain groups per l
  for (int ch = 0; ch < nch; ++ch) {
    int b0 = ch * NB;
    k_ln1 <<<NB * 4,   256, 0, stream>>>(inputs, ln1w, ln1b, xr, xi, b0);
    k_lstm<<<24 * nbq,  64, 0, stream>>>(xr, xi, wbf, bihh, Whh, hbuf, NB, nbq);
    k_attn<<<8 * NB,   256, 0, stream>>>(hbuf, att, NB);
    k_out <<<NB * 5,   256, 0, stream>>>(att, inputs, ln2w, ln2b, lrw, lrb,
                                         liw, lib, ln3w, ln3b, pa, out, b0, NB);
  }
}